// Round 4
// baseline (2172.586 us; speedup 1.0000x reference)
//
#include <hip/hip_runtime.h>
#include <math.h>

// Problem constants (fixed by reference)
#define DIMD 256
#define KCODES 4096
#define NROWS 65536
#define QN (NROWS * DIMD)   // 16777216 quantized elements

// Tiling for the fused distance+argmin kernel
constexpr int BM = 64;     // rows per block
constexpr int BN = 256;    // codes per tile
constexpr int BK = 32;     // D-chunk
constexpr int XS = BK + 4; // xs stride (36, mult of 4 for float4 stores)
constexpr int ES = BN + 2; // es_t stride (258, even for float2 reads)

// Opaque barrier: forces v to be a rounded fp32 value (blocks FMA contraction)
__device__ __forceinline__ float opaque(float v) {
    asm volatile("" : "+v"(v));
    return v;
}

// numpy pairwise_sum of 256 fp32 squares, bit-exact replication:
// n=256 -> pairwise(128) + pairwise(128); each 128-block: 8 accumulators
// r[j] over i = j, 8+j, ..., 120+j; combine ((r0+r1)+(r2+r3))+((r4+r5)+(r6+r7)).
// Products x_i*x_i are rounded to fp32 BEFORE summation (numpy makes a temp).
__device__ __forceinline__ float np_sumsq_256(const float* __restrict__ p) {
    float total = 0.0f;
    #pragma unroll
    for (int half = 0; half < 2; ++half) {
        const float* b = p + half * 128;
        float r[8];
        #pragma unroll
        for (int j = 0; j < 8; ++j) {
            const float v = b[j];
            r[j] = opaque(v * v);
        }
        for (int i = 8; i < 128; i += 8) {
            #pragma unroll
            for (int j = 0; j < 8; ++j) {
                const float v = b[i + j];
                r[j] += opaque(v * v);
            }
        }
        const float res = ((r[0] + r[1]) + (r[2] + r[3])) + ((r[4] + r[5]) + (r[6] + r[7]));
        total = (half == 0) ? res : (total + res);
    }
    return total;
}

// ---------------------------------------------------------------- kernel Sx
// s_x[n] = np.sum(x[n]*x[n]) with numpy pairwise semantics; 1 thread/row
__global__ void sx_kernel(const float* __restrict__ x, float* __restrict__ sx) {
    const int row = blockIdx.x * blockDim.x + threadIdx.x;
    sx[row] = np_sumsq_256(x + (size_t)row * DIMD);
}

// ---------------------------------------------------------------- kernel Se
// s_e[k] = np.sum(emb[k]*emb[k]) with numpy pairwise semantics; 1 thread/code
__global__ void se_kernel(const float* __restrict__ emb, float* __restrict__ se) {
    const int k = blockIdx.x * blockDim.x + threadIdx.x;
    se[k] = np_sumsq_256(emb + (size_t)k * DIMD);
}

// ---------------------------------------------------------------- kernel B
// Fused distance + argmin replicating np fp32 semantics:
//   dist = fl( fl(s_x - 2*dot) + s_e )   (2*dot exact => FMA-fuse harmless)
// First-occurrence argmin (ascending code order per thread + index tie-break).
__global__ __launch_bounds__(256, 3)
void distargmin_kernel(const float* __restrict__ x, const float* __restrict__ emb,
                       const float* __restrict__ sx, const float* __restrict__ se,
                       int* __restrict__ out_idx) {
    __shared__ float lds[BM * XS + BK * ES + BN]; // 10816 floats (43.3 KB)
    float* xs  = lds;                 // [BM][XS]   x chunk, row-major
    float* est = lds + BM * XS;       // [BK][ES]   emb chunk, TRANSPOSED: [dd][code]
    float* ens = est + BK * ES;       // [BN]       s_e for current tile

    const int t  = threadIdx.x;
    const int tc = t & 15;            // code-group 0..15
    const int tr = t >> 4;            // row-group 0..15 (4 rows each)
    const int row0 = blockIdx.x * BM;

    float sxv[4];
    #pragma unroll
    for (int i = 0; i < 4; ++i) sxv[i] = sx[row0 + tr * 4 + i];

    float mval[4] = {INFINITY, INFINITY, INFINITY, INFINITY};
    int   midx[4] = {0, 0, 0, 0};

    for (int tile = 0; tile < KCODES / BN; ++tile) {
        const int code0 = tile * BN;
        float acc[4][16];
        #pragma unroll
        for (int i = 0; i < 4; ++i)
            #pragma unroll
            for (int j = 0; j < 16; ++j) acc[i][j] = 0.0f;

        for (int ck = 0; ck < DIMD / BK; ++ck) {
            const int d0 = ck * BK;
            __syncthreads();  // protect LDS from previous readers
            // stage x chunk: thread -> row t/4, cols (t%4)*8 .. +7
            {
                const int r = t >> 2, c = (t & 3) * 8;
                const float4* src = (const float4*)(x + (size_t)(row0 + r) * DIMD + d0 + c);
                float4 v0 = src[0], v1 = src[1];
                *(float4*)&xs[r * XS + c]     = v0;
                *(float4*)&xs[r * XS + c + 4] = v1;
            }
            // stage emb chunk transposed: 8 passes, 8 lanes per code row
            #pragma unroll
            for (int q = 0; q < 8; ++q) {
                const int c  = q * 32 + (t >> 3);
                const int dd = (t & 7) * 4;
                float4 v = *(const float4*)(emb + (size_t)(code0 + c) * DIMD + d0 + dd);
                est[(dd + 0) * ES + c] = v.x;
                est[(dd + 1) * ES + c] = v.y;
                est[(dd + 2) * ES + c] = v.z;
                est[(dd + 3) * ES + c] = v.w;
            }
            if (ck == 0) ens[t] = se[code0 + t];
            __syncthreads();

            #pragma unroll 2
            for (int dd = 0; dd < BK; ++dd) {
                const float a0 = xs[(tr * 4 + 0) * XS + dd];
                const float a1 = xs[(tr * 4 + 1) * XS + dd];
                const float a2 = xs[(tr * 4 + 2) * XS + dd];
                const float a3 = xs[(tr * 4 + 3) * XS + dd];
                #pragma unroll
                for (int p = 0; p < 8; ++p) {
                    const float2 b = *(const float2*)&est[dd * ES + tc * 2 + p * 32];
                    acc[0][2 * p]     += a0 * b.x;  acc[0][2 * p + 1] += a0 * b.y;
                    acc[1][2 * p]     += a1 * b.x;  acc[1][2 * p + 1] += a1 * b.y;
                    acc[2][2 * p]     += a2 * b.x;  acc[2][2 * p + 1] += a2 * b.y;
                    acc[3][2 * p]     += a3 * b.x;  acc[3][2 * p + 1] += a3 * b.y;
                }
            }
        }
        // argmin update: np semantics. Per-thread codes ascend (p,e order),
        // strict < keeps first occurrence.
        #pragma unroll
        for (int p = 0; p < 8; ++p) {
            const float2 se2 = *(const float2*)&ens[tc * 2 + p * 32];
            #pragma unroll
            for (int e = 0; e < 2; ++e) {
                const float sek = e ? se2.y : se2.x;
                const int code = code0 + tc * 2 + p * 32 + e;
                #pragma unroll
                for (int i = 0; i < 4; ++i) {
                    const float t1   = sxv[i] - 2.0f * acc[i][2 * p + e]; // fl(s_x - 2*dot)
                    const float dist = t1 + sek;                          // fl(t1 + s_e)
                    if (dist < mval[i]) { mval[i] = dist; midx[i] = code; }
                }
            }
        }
    }

    // cross-thread reduce: 16 threads (tc) share each row; lowest-index tie-break
    __syncthreads();
    float* rv = lds;                   // [64][16] values
    int*   ri = (int*)(lds + 1024);    // [64][16] indices
    #pragma unroll
    for (int i = 0; i < 4; ++i) {
        rv[(tr * 4 + i) * 16 + tc] = mval[i];
        ri[(tr * 4 + i) * 16 + tc] = midx[i];
    }
    __syncthreads();
    if (t < BM) {
        float bv = rv[t * 16];
        int   bi = ri[t * 16];
        #pragma unroll
        for (int q2 = 1; q2 < 16; ++q2) {
            const float v = rv[t * 16 + q2];
            const int  id = ri[t * 16 + q2];
            if (v < bv || (v == bv && id < bi)) { bv = v; bi = id; }
        }
        out_idx[row0 + t] = bi;
    }
}

// ---------------------------------------------------------------- kernel Z
__global__ void zero_loss_kernel(float* __restrict__ out) {
    out[QN] = 0.0f;
}

// ---------------------------------------------------------------- kernel C
// gather emb[idx] -> quantized, write indices as float, accumulate loss
__global__ void gather_loss_kernel(const float* __restrict__ x, const float* __restrict__ emb,
                                   const int* __restrict__ idxs, float* __restrict__ out) {
    const int w = threadIdx.x >> 6, lane = threadIdx.x & 63;
    const int row = blockIdx.x * 4 + w;
    const int idx = idxs[row];
    const float4 e4 = ((const float4*)(emb + (size_t)idx * DIMD))[lane];
    const float4 x4 = ((const float4*)(x + (size_t)row * DIMD))[lane];
    ((float4*)(out + (size_t)row * DIMD))[lane] = e4;
    const float dx = e4.x - x4.x, dy = e4.y - x4.y, dz = e4.z - x4.z, dw = e4.w - x4.w;
    float s = dx * dx + dy * dy + dz * dz + dw * dw;
    #pragma unroll
    for (int off = 32; off > 0; off >>= 1) s += __shfl_down(s, off, 64);
    __shared__ float wsum[4];
    if (lane == 0) wsum[w] = s;
    __syncthreads();
    if (threadIdx.x == 0) {
        const float tot = wsum[0] + wsum[1] + wsum[2] + wsum[3];
        atomicAdd(out + QN, tot * (1.25f / (float)QN));
    }
    if (lane == 0) out[QN + 1 + row] = (float)idx;
}

// ---------------------------------------------------------------- launcher
extern "C" void kernel_launch(void* const* d_in, const int* in_sizes, int n_in,
                              void* d_out, int out_size, void* d_ws, size_t ws_size,
                              hipStream_t stream) {
    const float* x   = (const float*)d_in[0];   // [65536, 256]
    const float* emb = (const float*)d_in[1];   // [4096, 256]
    float* out = (float*)d_out;                 // q[16777216] | loss[1] | idx[65536]

    float* sx  = (float*)d_ws;                                  // 65536 floats
    float* se  = (float*)((char*)d_ws + NROWS * 4);             // 4096 floats
    int*   idx = (int*)((char*)d_ws + NROWS * 4 + KCODES * 4);  // 65536 ints

    sx_kernel<<<NROWS / 256, 256, 0, stream>>>(x, sx);
    se_kernel<<<KCODES / 256, 256, 0, stream>>>(emb, se);
    distargmin_kernel<<<NROWS / BM, 256, 0, stream>>>(x, emb, sx, se, idx);
    zero_loss_kernel<<<1, 1, 0, stream>>>(out);
    gather_loss_kernel<<<NROWS / 4, 256, 0, stream>>>(x, emb, idx, out);
}